// Round 1
// baseline (810.375 us; speedup 1.0000x reference)
//
#include <hip/hip_runtime.h>

typedef unsigned short u16;
typedef int   v4i __attribute__((ext_vector_type(4)));
typedef float v4f __attribute__((ext_vector_type(4)));

// ---------- helpers ----------
__device__ __forceinline__ float b2f(u16 v) {
    union { unsigned u; float f; } t; t.u = ((unsigned)v) << 16; return t.f;
}
__device__ __forceinline__ u16 f2b(float f) {
    union { float f; unsigned u; } t; t.f = f;
    unsigned r = (t.u + 0x7FFFu + ((t.u >> 16) & 1u)) >> 16;
    return (u16)r;
}
__device__ __forceinline__ v4f mfma16(v4i a, v4i b, v4f c) {
    asm("v_mfma_f32_16x16x32_bf16 %0, %1, %2, %0" : "+v"(c) : "v"(a), "v"(b));
    return c;
}

// ---------- weight f32->bf16 convert ----------
struct WCvt { const float* s[11]; u16* d[11]; int n[11]; };
__global__ void cvt_weights(WCvt p) {
    int wi = blockIdx.y;
    int i = blockIdx.x * 256 + threadIdx.x;
    if (i < p.n[wi]) p.d[wi][i] = f2b(p.s[wi][i]);
}

// ---------- transpose+convert x,y: [B,C,N] f32 -> [B,N,C] bf16 ----------
__global__ __launch_bounds__(256) void transpose_cvt(
    const float* __restrict__ x, const float* __restrict__ y,
    u16* __restrict__ xt, u16* __restrict__ yt)
{
    const int z = blockIdx.z, t = z >> 2, b = z & 3;
    const float* src = t ? y : x;
    u16* dst = t ? yt : xt;
    __shared__ float tile[32][33];
    const int nt = blockIdx.x * 32, ct = blockIdx.y * 32;
    const int tx = threadIdx.x, ty = threadIdx.y;
#pragma unroll
    for (int i = 0; i < 4; i++)
        tile[ty + i * 8][tx] = src[((long)b * 256 + ct + ty + i * 8) * 4096 + nt + tx];
    __syncthreads();
#pragma unroll
    for (int i = 0; i < 4; i++)
        dst[((long)b * 4096 + nt + ty + i * 8) * 256 + ct + tx] = f2b(tile[tx][ty + i * 8]);
}

// ---------- small path: zv = Wv@z, mv = Wv@m, mline = mv@Wfc^T + bfc ----------
__global__ void small_zm(const float* __restrict__ z, const float* __restrict__ m,
                         const float* __restrict__ Wv, const float* __restrict__ Wfc,
                         const float* __restrict__ bfc,
                         float* __restrict__ zv, float* __restrict__ mline)
{
    const int o = blockIdx.x, b = blockIdx.y, tid = threadIdx.x; // block 64
    __shared__ float wrow[256];
    __shared__ float mvs[9];
    for (int i = tid; i < 256; i += 64) wrow[i] = Wv[o * 256 + i];
    __syncthreads();
    if (tid < 36) {
        float s = 0.f;
        for (int c = 0; c < 256; c++) s += wrow[c] * z[((long)b * 256 + c) * 36 + tid];
        zv[((long)b * 256 + o) * 36 + tid] = s;
    }
    if (tid < 9) {
        float s = 0.f;
        for (int c = 0; c < 256; c++) s += wrow[c] * m[((long)b * 256 + c) * 9 + tid];
        mvs[tid] = s;
    }
    __syncthreads();
    if (tid < 36) {
        float s = bfc[tid];
        for (int k = 0; k < 9; k++) s += mvs[k] * Wfc[tid * 9 + k];
        mline[((long)b * 256 + o) * 36 + tid] = s;
    }
}

// ---------- F = z_line @ m_line^T (+I), stored bf16 row-major [B][C][C] ----------
__global__ void small_F(const float* __restrict__ zv, const float* __restrict__ mline,
                        u16* __restrict__ Fb)
{
    const int c = blockIdx.x, b = blockIdx.y, d = threadIdx.x; // 256 threads
    const float* zr = zv + ((long)b * 256 + c) * 36;
    const float* mr = mline + ((long)b * 256 + d) * 36;
    float s = (c == d) ? 1.f : 0.f;
    for (int n = 0; n < 36; n++) s += zr[n] * mr[n];
    Fb[((long)b * 256 + c) * 256 + d] = f2b(s);
}

// ---------- generic GEMM: out[n][o] = sum_k X[n][k] * W[o][k] (+bias[o]) ----------
// X: [rows=4096][ldx] bf16 per batch; W: [O][ldw] bf16 (wbs: per-batch stride, 0=shared)
// outT: [n][o] layout (ldot, otbs); outN: [o][n] layout (ldon, onbs)
__global__ __launch_bounds__(256) void gemm_tn(
    const u16* __restrict__ X, int ldx, long xbs,
    const u16* __restrict__ W, int ldw, long wbs,
    const float* __restrict__ bias,
    u16* __restrict__ outT, int ldot, long otbs,
    u16* __restrict__ outN, int ldon, long onbs,
    int K, int wt, int wn)
{
    const int b = blockIdx.z;
    const int n0 = blockIdx.x * 128, o0 = blockIdx.y * 128;
    const int tid = threadIdx.x, lane = tid & 63, w = tid >> 6;
    const int l15 = lane & 15, lg = lane >> 4;
    const int wr = (w >> 1) * 64, wc = (w & 1) * 64;
    const u16* Xp = X + b * xbs + (long)(n0 + wr + l15) * ldx + lg * 8;
    const u16* Wp = W + b * wbs + (long)(o0 + wc + l15) * ldw + lg * 8;

    v4f acc[4][4];
    for (int oi = 0; oi < 4; oi++) {
        float bv = bias ? bias[o0 + wc + oi * 16 + l15] : 0.f;
        for (int mi = 0; mi < 4; mi++) acc[mi][oi] = (v4f){bv, bv, bv, bv};
    }
    for (int k = 0; k < K; k += 32) {
        v4i a[4], bb[4];
#pragma unroll
        for (int mi = 0; mi < 4; mi++) a[mi] = *(const v4i*)(Xp + (long)mi * 16 * ldx + k);
#pragma unroll
        for (int oi = 0; oi < 4; oi++) bb[oi] = *(const v4i*)(Wp + (long)oi * 16 * ldw + k);
#pragma unroll
        for (int mi = 0; mi < 4; mi++)
#pragma unroll
            for (int oi = 0; oi < 4; oi++)
                acc[mi][oi] = mfma16(a[mi], bb[oi], acc[mi][oi]);
    }
    for (int mi = 0; mi < 4; mi++)
        for (int oi = 0; oi < 4; oi++) {
            int nn = n0 + wr + mi * 16 + lg * 4;
            int oo = o0 + wc + oi * 16 + l15;
            if (wt) {
                u16* p = outT + b * otbs + (long)nn * ldot + oo;
#pragma unroll
                for (int r = 0; r < 4; r++) p[(long)r * ldot] = f2b(acc[mi][oi][r]);
            }
            if (wn) {
                ushort4 pk;
                pk.x = f2b(acc[mi][oi][0]); pk.y = f2b(acc[mi][oi][1]);
                pk.z = f2b(acc[mi][oi][2]); pk.w = f2b(acc[mi][oi][3]);
                *(ushort4*)(outN + b * onbs + (long)oo * ldon + nn) = pk;
            }
        }
}

// ---------- fused attention (both branches), no-max softmax ----------
// Qt,Kt: [B][N][C] bf16 (transposed); V: [B][C][N] bf16 (natural)
// Ot: [B][N][C] bf16 (gamma-scaled); On: [B][C][N] bf16 (gamma-scaled)
__global__ __launch_bounds__(256) void attn_kernel(
    const u16* __restrict__ qtA, const u16* __restrict__ ktA, const u16* __restrict__ vA,
    u16* __restrict__ otA, u16* __restrict__ onA, const float* __restrict__ gA,
    const u16* __restrict__ qtB, const u16* __restrict__ ktB, const u16* __restrict__ vB,
    u16* __restrict__ otB, u16* __restrict__ onB, const float* __restrict__ gB)
{
    const int qb = blockIdx.x, br = blockIdx.y, b = blockIdx.z;
    const u16* Qt = br ? qtB : qtA;
    const u16* Kt = br ? ktB : ktA;
    const u16* V  = br ? vB  : vA;
    u16* Ot = br ? otB : otA;
    u16* On = br ? onB : onA;
    const float gamma = br ? gB[0] : gA[0];
    const long bs = (long)4096 * 256;
    const u16* Qb = Qt + b * bs;
    const u16* Kb = Kt + b * bs;
    const u16* Vb = V + b * bs;
    u16* Otb = Ot + b * bs;
    u16* Onb = On + b * bs;

    const int tid = threadIdx.x, lane = tid & 63, w = tid >> 6;
    const int l15 = lane & 15, lg = lane >> 4;

    __shared__ __align__(16) u16 P[64][72];   // row stride 144B (16B aligned)
    __shared__ float den[64];

    // preload Q fragments: wave w owns query rows [qb*64 + w*16, +16)
    v4i qf[8];
    const u16* qp = Qb + (long)(qb * 64 + w * 16 + l15) * 256 + lg * 8;
#pragma unroll
    for (int ks = 0; ks < 8; ks++) qf[ks] = *(const v4i*)(qp + ks * 32);

    v4f oacc[4][4];
    for (int ci = 0; ci < 4; ci++)
        for (int qi = 0; qi < 4; qi++) oacc[ci][qi] = (v4f){0.f, 0.f, 0.f, 0.f};
    float dacc[4] = {0.f, 0.f, 0.f, 0.f};

    const u16* kb = Kb + (long)l15 * 256 + lg * 8;
    const u16* vb = Vb + (long)(w * 64 + l15) * 4096 + lg * 8;

    for (int mb = 0; mb < 64; ++mb) {
        // QK^T: L[16 own q][64 m]
        v4f lacc[4];
#pragma unroll
        for (int mi = 0; mi < 4; mi++) lacc[mi] = (v4f){0.f, 0.f, 0.f, 0.f};
#pragma unroll
        for (int ks = 0; ks < 8; ks++) {
            v4i kf[4];
#pragma unroll
            for (int mi = 0; mi < 4; mi++)
                kf[mi] = *(const v4i*)(kb + (long)(mb * 64 + mi * 16) * 256 + ks * 32);
#pragma unroll
            for (int mi = 0; mi < 4; mi++) lacc[mi] = mfma16(qf[ks], kf[mi], lacc[mi]);
        }
        // exp -> P (bf16), denominator accumulation
#pragma unroll
        for (int mi = 0; mi < 4; mi++) {
#pragma unroll
            for (int r = 0; r < 4; r++) {
                float e = __expf(lacc[mi][r]);
                dacc[r] += e;
                P[w * 16 + lg * 4 + r][mi * 16 + l15] = f2b(e);
            }
        }
        __syncthreads();
        // PV: O^T slice = V (c-slice) * P^T ; wave w owns channels [w*64, w*64+64)
#pragma unroll
        for (int ks2 = 0; ks2 < 2; ks2++) {
            v4i pf[4], vf[4];
#pragma unroll
            for (int qi = 0; qi < 4; qi++)
                pf[qi] = *(const v4i*)(&P[qi * 16 + l15][ks2 * 32 + lg * 8]);
#pragma unroll
            for (int ci = 0; ci < 4; ci++)
                vf[ci] = *(const v4i*)(vb + (long)ci * 16 * 4096 + mb * 64 + ks2 * 32);
#pragma unroll
            for (int ci = 0; ci < 4; ci++)
#pragma unroll
                for (int qi = 0; qi < 4; qi++)
                    oacc[ci][qi] = mfma16(vf[ci], pf[qi], oacc[ci][qi]);
        }
        __syncthreads();
    }

    // reduce denominator across the 16-lane group (covers all m)
#pragma unroll
    for (int r = 0; r < 4; r++) {
        float s = dacc[r];
        s += __shfl_xor(s, 1); s += __shfl_xor(s, 2);
        s += __shfl_xor(s, 4); s += __shfl_xor(s, 8);
        if (l15 == 0) den[w * 16 + lg * 4 + r] = s;
    }
    __syncthreads();

    // epilogue: scale by gamma/den, write both layouts
    for (int qi = 0; qi < 4; qi++) {
        int q = qi * 16 + l15;
        float sc = gamma / den[q];
        int n = qb * 64 + q;
        for (int ci = 0; ci < 4; ci++) {
            int c0 = w * 64 + ci * 16 + lg * 4;
            ushort4 pk;
            pk.x = f2b(oacc[ci][qi][0] * sc);
            pk.y = f2b(oacc[ci][qi][1] * sc);
            pk.z = f2b(oacc[ci][qi][2] * sc);
            pk.w = f2b(oacc[ci][qi][3] * sc);
            *(ushort4*)(Otb + (long)n * 256 + c0) = pk;
            Onb[(long)(c0 + 0) * 4096 + n] = pk.x;
            Onb[(long)(c0 + 1) * 4096 + n] = pk.y;
            Onb[(long)(c0 + 2) * 4096 + n] = pk.z;
            Onb[(long)(c0 + 3) * 4096 + n] = pk.w;
        }
    }
}

// ---------- final gate + combine ----------
__global__ __launch_bounds__(256) void combine_kernel(
    const u16* __restrict__ On, const u16* __restrict__ O2n,
    const u16* __restrict__ H5, const u16* __restrict__ H6,
    const float* __restrict__ x, float* __restrict__ out)
{
    long i = ((long)blockIdx.x * 256 + threadIdx.x) * 4;
    ushort4 a  = *(const ushort4*)(On + i);
    ushort4 c2 = *(const ushort4*)(O2n + i);
    ushort4 h5 = *(const ushort4*)(H5 + i);
    ushort4 h6 = *(const ushort4*)(H6 + i);
    float4 xv = *(const float4*)(x + i);
    u16 av[4] = {a.x, a.y, a.z, a.w};
    u16 cv[4] = {c2.x, c2.y, c2.z, c2.w};
    u16 h5v[4] = {h5.x, h5.y, h5.z, h5.w};
    u16 h6v[4] = {h6.x, h6.y, h6.z, h6.w};
    float xr[4] = {xv.x, xv.y, xv.z, xv.w};
    float o[4];
#pragma unroll
    for (int j = 0; j < 4; j++) {
        float s5 = 1.f / (1.f + __expf(-b2f(h5v[j])));
        float s6 = 1.f / (1.f + __expf(-b2f(h6v[j])));
        float w0 = 1.f / (1.f + __expf(s6 - s5));   // softmax([s5,s6])[0]
        o[j] = w0 * b2f(av[j]) + (1.f - w0) * b2f(cv[j]) + xr[j];
    }
    *(float4*)(out + i) = make_float4(o[0], o[1], o[2], o[3]);
}

// ---------- host ----------
extern "C" void kernel_launch(void* const* d_in, const int* in_sizes, int n_in,
                              void* d_out, int out_size, void* d_ws, size_t ws_size,
                              hipStream_t stream)
{
    const float* x     = (const float*)d_in[0];
    const float* y     = (const float*)d_in[1];
    const float* z     = (const float*)d_in[2];
    const float* m     = (const float*)d_in[3];
    const float* Wv    = (const float*)d_in[4];
    const float* Wv2   = (const float*)d_in[5];
    const float* Wq    = (const float*)d_in[6];
    const float* bq    = (const float*)d_in[7];
    const float* Wk    = (const float*)d_in[8];
    const float* bk    = (const float*)d_in[9];
    const float* Wq2   = (const float*)d_in[10];
    const float* bq2   = (const float*)d_in[11];
    const float* Wk2   = (const float*)d_in[12];
    const float* bk2   = (const float*)d_in[13];
    const float* Win1  = (const float*)d_in[14];
    const float* bin1  = (const float*)d_in[15];
    const float* Win3  = (const float*)d_in[16];
    const float* bin3  = (const float*)d_in[17];
    const float* Wtr   = (const float*)d_in[18];
    const float* btr   = (const float*)d_in[19];
    const float* Wout2 = (const float*)d_in[20];
    const float* bout2 = (const float*)d_in[21];
    const float* Wout3 = (const float*)d_in[22];
    const float* bout3 = (const float*)d_in[23];
    const float* Wfc   = (const float*)d_in[24];
    const float* bfc   = (const float*)d_in[25];
    const float* gamma  = (const float*)d_in[26];
    const float* gamma2 = (const float*)d_in[27];

    char* ws = (char*)d_ws;
    // weight area
    u16* Wb[10];
    for (int i = 0; i < 10; i++) Wb[i] = (u16*)(ws + (size_t)i * 131072);
    u16* Wtrb = (u16*)(ws + 1310720);
    u16* Fb   = (u16*)(ws + 2097152);
    float* zv    = (float*)(ws + 2621440);
    float* mline = (float*)(ws + 2768896);
    // big slots (8MB each) starting at 4MB
    auto SLOT = [&](int i) { return ws + 4194304 + (size_t)i * 8388608; };
    u16* xt  = (u16*)SLOT(0);
    u16* yt  = (u16*)SLOT(1);
    u16* yvt = (u16*)SLOT(2);
    u16* fmt = (u16*)SLOT(3);
    u16* fmn = (u16*)SLOT(4);
    u16* v2n = (u16*)SLOT(5);
    u16* qt  = (u16*)SLOT(6);
    u16* kt  = (u16*)SLOT(7);
    u16* q2t = (u16*)SLOT(8);
    u16* k2t = (u16*)SLOT(9);
    // reuse after their producers/consumers are done:
    u16* O2n = (u16*)SLOT(0);   // xt dead
    u16* Ot_ = (u16*)SLOT(1);   // yt dead
    u16* On_ = (u16*)SLOT(2);   // yvt dead
    u16* O2t = (u16*)SLOT(3);   // fmt dead
    u16* H13 = (u16*)SLOT(4);   // spans S4,S5 (fmn,v2n dead post-attention)
    u16* Htra = (u16*)SLOT(6);  // spans S6,S7 (qt,kt dead)
    u16* H5  = (u16*)SLOT(8);   // q2t dead
    u16* H6  = (u16*)SLOT(9);   // k2t dead

    const long NC = 4096L * 256, N512 = 4096L * 512, CC = 65536;

    // 1. convert weights
    WCvt wc;
    const float* wsrc[11] = {Wv, Wv2, Wq, Wk, Wq2, Wk2, Win1, Win3, Wout2, Wout3, Wtr};
    u16* wdst[11] = {Wb[0], Wb[1], Wb[2], Wb[3], Wb[4], Wb[5], Wb[6], Wb[7], Wb[8], Wb[9], Wtrb};
    for (int i = 0; i < 11; i++) { wc.s[i] = wsrc[i]; wc.d[i] = wdst[i]; wc.n[i] = (i == 10) ? 262144 : 65536; }
    cvt_weights<<<dim3(1024, 11), 256, 0, stream>>>(wc);

    // 2. transpose+convert x,y
    transpose_cvt<<<dim3(128, 8, 8), dim3(32, 8), 0, stream>>>(x, y, xt, yt);

    // 3. small path
    small_zm<<<dim3(256, 4), 64, 0, stream>>>(z, m, Wv, Wfc, bfc, zv, mline);
    small_F<<<dim3(256, 4), 256, 0, stream>>>(zv, mline, Fb);

    // 4. projections
    // yvt = yt * Wv^T                                   -> [N,C]
    gemm_tn<<<dim3(32, 2, 4), 256, 0, stream>>>(yt, 256, NC, Wb[0], 256, 0, nullptr,
                                                yvt, 256, NC, nullptr, 0, 0, 256, 1, 0);
    // fuse_mzy = (F+I) * yv   -> fmt [N,C] and fmn [C,N]
    gemm_tn<<<dim3(32, 2, 4), 256, 0, stream>>>(yvt, 256, NC, Fb, 256, CC, nullptr,
                                                fmt, 256, NC, fmn, 4096, NC, 256, 1, 1);
    // qt = xt*Wq^T+bq ; kt = fmt*Wk^T+bk ; q2t, k2t ; v2n = xt*Wv2^T (natural)
    gemm_tn<<<dim3(32, 2, 4), 256, 0, stream>>>(xt, 256, NC, Wb[2], 256, 0, bq,
                                                qt, 256, NC, nullptr, 0, 0, 256, 1, 0);
    gemm_tn<<<dim3(32, 2, 4), 256, 0, stream>>>(fmt, 256, NC, Wb[3], 256, 0, bk,
                                                kt, 256, NC, nullptr, 0, 0, 256, 1, 0);
    gemm_tn<<<dim3(32, 2, 4), 256, 0, stream>>>(xt, 256, NC, Wb[4], 256, 0, bq2,
                                                q2t, 256, NC, nullptr, 0, 0, 256, 1, 0);
    gemm_tn<<<dim3(32, 2, 4), 256, 0, stream>>>(xt, 256, NC, Wb[5], 256, 0, bk2,
                                                k2t, 256, NC, nullptr, 0, 0, 256, 1, 0);
    gemm_tn<<<dim3(32, 2, 4), 256, 0, stream>>>(xt, 256, NC, Wb[1], 256, 0, nullptr,
                                                nullptr, 0, 0, v2n, 4096, NC, 256, 0, 1);

    // 5. both attention branches (gamma applied at epilogue)
    attn_kernel<<<dim3(64, 2, 4), 256, 0, stream>>>(qt, kt, fmn, Ot_, On_, gamma,
                                                    q2t, k2t, v2n, O2t, O2n, gamma2);

    // 6. gating epilogue
    gemm_tn<<<dim3(32, 2, 4), 256, 0, stream>>>(Ot_, 256, NC, Wb[6], 256, 0, bin1,
                                                H13, 512, N512, nullptr, 0, 0, 256, 1, 0);
    gemm_tn<<<dim3(32, 2, 4), 256, 0, stream>>>(O2t, 256, NC, Wb[7], 256, 0, bin3,
                                                H13 + 256, 512, N512, nullptr, 0, 0, 256, 1, 0);
    gemm_tn<<<dim3(32, 4, 4), 256, 0, stream>>>(H13, 512, N512, Wtrb, 512, 0, btr,
                                                Htra, 512, N512, nullptr, 0, 0, 512, 1, 0);
    gemm_tn<<<dim3(32, 2, 4), 256, 0, stream>>>(Htra, 512, N512, Wb[8], 256, 0, bout2,
                                                nullptr, 0, 0, H5, 4096, NC, 256, 0, 1);
    gemm_tn<<<dim3(32, 2, 4), 256, 0, stream>>>(Htra + 256, 512, N512, Wb[9], 256, 0, bout3,
                                                nullptr, 0, 0, H6, 4096, NC, 256, 0, 1);

    // 7. combine
    combine_kernel<<<4096, 256, 0, stream>>>(On_, O2n, H5, H6, x, (float*)d_out);
}

// Round 2
// 407.876 us; speedup vs baseline: 1.9868x; 1.9868x over previous
//
#include <hip/hip_runtime.h>

typedef unsigned short u16;
typedef int   v4i __attribute__((ext_vector_type(4)));
typedef float v4f __attribute__((ext_vector_type(4)));

// ---------- helpers ----------
__device__ __forceinline__ float b2f(u16 v) {
    union { unsigned u; float f; } t; t.u = ((unsigned)v) << 16; return t.f;
}
__device__ __forceinline__ u16 f2b(float f) {
    union { float f; unsigned u; } t; t.f = f;
    unsigned r = (t.u + 0x7FFFu + ((t.u >> 16) & 1u)) >> 16;
    return (u16)r;
}
__device__ __forceinline__ v4f mfma16(v4i a, v4i b, v4f c) {
    asm("v_mfma_f32_16x16x32_bf16 %0, %1, %2, %0" : "+v"(c) : "v"(a), "v"(b));
    return c;
}
__device__ __forceinline__ void gload16(const u16* g, u16* l) {
    __builtin_amdgcn_global_load_lds(
        (const __attribute__((address_space(1))) unsigned int*)g,
        (__attribute__((address_space(3))) unsigned int*)l,
        16, 0, 0);
}

// ---------- weight f32->bf16 convert ----------
struct WCvt { const float* s[11]; u16* d[11]; int n[11]; };
__global__ void cvt_weights(WCvt p) {
    int wi = blockIdx.y;
    int i = blockIdx.x * 256 + threadIdx.x;
    if (i < p.n[wi]) p.d[wi][i] = f2b(p.s[wi][i]);
}

// ---------- transpose+convert x,y: [B,C,N] f32 -> [B,N,C] bf16 ----------
__global__ __launch_bounds__(256) void transpose_cvt(
    const float* __restrict__ x, const float* __restrict__ y,
    u16* __restrict__ xt, u16* __restrict__ yt)
{
    const int z = blockIdx.z, t = z >> 2, b = z & 3;
    const float* src = t ? y : x;
    u16* dst = t ? yt : xt;
    __shared__ float tile[32][33];
    const int nt = blockIdx.x * 32, ct = blockIdx.y * 32;
    const int tx = threadIdx.x, ty = threadIdx.y;
#pragma unroll
    for (int i = 0; i < 4; i++)
        tile[ty + i * 8][tx] = src[((long)b * 256 + ct + ty + i * 8) * 4096 + nt + tx];
    __syncthreads();
#pragma unroll
    for (int i = 0; i < 4; i++)
        dst[((long)b * 4096 + nt + ty + i * 8) * 256 + ct + tx] = f2b(tile[tx][ty + i * 8]);
}

// ---------- small path ----------
__global__ void small_zm(const float* __restrict__ z, const float* __restrict__ m,
                         const float* __restrict__ Wv, const float* __restrict__ Wfc,
                         const float* __restrict__ bfc,
                         float* __restrict__ zv, float* __restrict__ mline)
{
    const int o = blockIdx.x, b = blockIdx.y, tid = threadIdx.x; // block 64
    __shared__ float wrow[256];
    __shared__ float mvs[9];
    for (int i = tid; i < 256; i += 64) wrow[i] = Wv[o * 256 + i];
    __syncthreads();
    if (tid < 36) {
        float s = 0.f;
        for (int c = 0; c < 256; c++) s += wrow[c] * z[((long)b * 256 + c) * 36 + tid];
        zv[((long)b * 256 + o) * 36 + tid] = s;
    }
    if (tid < 9) {
        float s = 0.f;
        for (int c = 0; c < 256; c++) s += wrow[c] * m[((long)b * 256 + c) * 9 + tid];
        mvs[tid] = s;
    }
    __syncthreads();
    if (tid < 36) {
        float s = bfc[tid];
        for (int k = 0; k < 9; k++) s += mvs[k] * Wfc[tid * 9 + k];
        mline[((long)b * 256 + o) * 36 + tid] = s;
    }
}

__global__ void small_F(const float* __restrict__ zv, const float* __restrict__ mline,
                        u16* __restrict__ Fb)
{
    const int c = blockIdx.x, b = blockIdx.y, d = threadIdx.x; // 256 threads
    const float* zr = zv + ((long)b * 256 + c) * 36;
    const float* mr = mline + ((long)b * 256 + d) * 36;
    float s = (c == d) ? 1.f : 0.f;
    for (int n = 0; n < 36; n++) s += zr[n] * mr[n];
    Fb[((long)b * 256 + c) * 256 + d] = f2b(s);
}

// ---------- merged GEMM: out[n][o] = sum_k X[n][k] * W[o][k] (+bias[o]) ----------
struct GDesc {
    const u16* X; const u16* W; const float* bias;
    u16* outT; u16* outN;
    long xbs, wbs, otbs, onbs;
    int ldx, ldw, ldot, ldon, K;
};
struct GJob { GDesc d[8]; int oblk; };

__global__ __launch_bounds__(256) void gemm_tn(GJob j) {
    const int di = blockIdx.y / j.oblk;
    const int o0 = (blockIdx.y % j.oblk) * 128;
    const GDesc g = j.d[di];
    const int b = blockIdx.z;
    const int n0 = blockIdx.x * 128;
    const int tid = threadIdx.x, lane = tid & 63, w = tid >> 6;
    const int l15 = lane & 15, lg = lane >> 4;
    const int wr = (w >> 1) * 64, wc = (w & 1) * 64;
    const u16* Xp = g.X + b * g.xbs + (long)(n0 + wr + l15) * g.ldx + lg * 8;
    const u16* Wp = g.W + b * g.wbs + (long)(o0 + wc + l15) * g.ldw + lg * 8;

    v4f acc[4][4];
    for (int oi = 0; oi < 4; oi++) {
        float bv = g.bias ? g.bias[o0 + wc + oi * 16 + l15] : 0.f;
        for (int mi = 0; mi < 4; mi++) acc[mi][oi] = (v4f){bv, bv, bv, bv};
    }
#pragma unroll 4
    for (int k = 0; k < g.K; k += 32) {
        v4i a[4], bb[4];
#pragma unroll
        for (int mi = 0; mi < 4; mi++) a[mi] = *(const v4i*)(Xp + (long)mi * 16 * g.ldx + k);
#pragma unroll
        for (int oi = 0; oi < 4; oi++) bb[oi] = *(const v4i*)(Wp + (long)oi * 16 * g.ldw + k);
#pragma unroll
        for (int mi = 0; mi < 4; mi++)
#pragma unroll
            for (int oi = 0; oi < 4; oi++)
                acc[mi][oi] = mfma16(a[mi], bb[oi], acc[mi][oi]);
    }
    for (int mi = 0; mi < 4; mi++)
        for (int oi = 0; oi < 4; oi++) {
            int nn = n0 + wr + mi * 16 + lg * 4;
            int oo = o0 + wc + oi * 16 + l15;
            if (g.outT) {
                u16* p = g.outT + b * g.otbs + (long)nn * g.ldot + oo;
#pragma unroll
                for (int r = 0; r < 4; r++) p[(long)r * g.ldot] = f2b(acc[mi][oi][r]);
            }
            if (g.outN) {
                ushort4 pk;
                pk.x = f2b(acc[mi][oi][0]); pk.y = f2b(acc[mi][oi][1]);
                pk.z = f2b(acc[mi][oi][2]); pk.w = f2b(acc[mi][oi][3]);
                *(ushort4*)(g.outN + b * g.onbs + (long)oo * g.ldon + nn) = pk;
            }
        }
}

// ---------- fused attention (both branches), no-max softmax ----------
// Qt,Kt: [B][N][C] bf16 (transposed); V: [B][C][N] bf16 (natural)
// K tiles (32 rows x 256 cols) LDS-staged, double-buffered, XOR-swizzled.
__global__ __launch_bounds__(256) void attn_kernel(
    const u16* __restrict__ qtA, const u16* __restrict__ ktA, const u16* __restrict__ vA,
    u16* __restrict__ otA, u16* __restrict__ onA, const float* __restrict__ gA,
    const u16* __restrict__ qtB, const u16* __restrict__ ktB, const u16* __restrict__ vB,
    u16* __restrict__ otB, u16* __restrict__ onB, const float* __restrict__ gB)
{
    const int qb = blockIdx.x, br = blockIdx.y, b = blockIdx.z;
    const u16* Qt = br ? qtB : qtA;
    const u16* Kt = br ? ktB : ktA;
    const u16* V  = br ? vB  : vA;
    u16* Ot = br ? otB : otA;
    u16* On = br ? onB : onA;
    const float gamma = br ? gB[0] : gA[0];
    const long bs = (long)4096 * 256;
    const u16* Qb = Qt + b * bs;
    const u16* Kb = Kt + b * bs;
    const u16* Vb = V + b * bs;
    u16* Otb = Ot + b * bs;
    u16* Onb = On + b * bs;

    const int tid = threadIdx.x, lane = tid & 63, w = tid >> 6;
    const int l15 = lane & 15, lg = lane >> 4;

    __shared__ __align__(16) u16 Ksh[2][8192];   // 2 x 32x256 bf16 = 32KB
    __shared__ __align__(16) u16 P[64][40];      // 64 q x 32 m, pad to 40
    __shared__ float den[64];

    // preload Q fragments: wave w owns query rows [qb*64 + w*16, +16)
    v4i qf[8];
    const u16* qp = Qb + (long)(qb * 64 + w * 16 + l15) * 256 + lg * 8;
#pragma unroll
    for (int ks = 0; ks < 8; ks++) qf[ks] = *(const v4i*)(qp + ks * 32);

    v4f oacc[4][4];
    for (int ci = 0; ci < 4; ci++)
        for (int qi = 0; qi < 4; qi++) oacc[ci][qi] = (v4f){0.f, 0.f, 0.f, 0.f};
    float dacc[4] = {0.f, 0.f, 0.f, 0.f};

    const u16* vb = Vb + (long)(w * 64 + l15) * 4096 + lg * 8;

    // stage geometry: wave w stages tile rows [w*8, w*8+8)
    const int srow = w * 8 + (lane >> 5);
    const int scolB = (lane & 31) * 16;        // linear column byte for this lane

    auto STAGE = [&](int buf, int t) {
        const u16* base = Kb + (long)t * 8192;   // tile t: rows [t*32, t*32+32)
        u16* lb = &Ksh[buf][w * 2048];
#pragma unroll
        for (int i = 0; i < 4; i++) {
            int row = srow + i * 2;
            int colB = scolB ^ ((row & 7) << 4);   // inverse swizzle on SOURCE
            gload16(base + row * 256 + (colB >> 1), lb + i * 512);
        }
    };

    STAGE(0, 0);
    __syncthreads();

    for (int mb = 0; mb < 128; ++mb) {
        const int cur = mb & 1;
        const u16* kb = &Ksh[cur][0];
        // QK^T: L[16 own q][32 m]
        v4f lacc[2];
        lacc[0] = (v4f){0.f, 0.f, 0.f, 0.f};
        lacc[1] = (v4f){0.f, 0.f, 0.f, 0.f};
        __builtin_amdgcn_s_setprio(1);
#pragma unroll
        for (int ks = 0; ks < 8; ks++) {
            v4i kf[2];
#pragma unroll
            for (int mi = 0; mi < 2; mi++) {
                int row = mi * 16 + l15;
                int colB = (ks * 64 + lg * 16) ^ ((row & 7) << 4);   // swizzled READ
                kf[mi] = *(const v4i*)(kb + row * 256 + (colB >> 1));
            }
            lacc[0] = mfma16(qf[ks], kf[0], lacc[0]);
            lacc[1] = mfma16(qf[ks], kf[1], lacc[1]);
        }
        __builtin_amdgcn_s_setprio(0);
        // prefetch next K tile (reads of Ksh[cur] already issued above)
        if (mb < 127) STAGE(cur ^ 1, mb + 1);
        // exp -> P (bf16), denominator accumulation
#pragma unroll
        for (int mi = 0; mi < 2; mi++)
#pragma unroll
            for (int r = 0; r < 4; r++) {
                float e = __expf(lacc[mi][r]);
                dacc[r] += e;
                P[w * 16 + lg * 4 + r][mi * 16 + l15] = f2b(e);
            }
        // P-ready barrier WITHOUT vmcnt drain (keep stage in flight)
        asm volatile("s_waitcnt lgkmcnt(0)" ::: "memory");
        __builtin_amdgcn_s_barrier();
        __builtin_amdgcn_sched_barrier(0);
        // PV: wave w owns channels [w*64, w*64+64), k-dim = 32 keys
        {
            v4i pf[4], vf[4];
#pragma unroll
            for (int qi = 0; qi < 4; qi++)
                pf[qi] = *(const v4i*)(&P[qi * 16 + l15][lg * 8]);
#pragma unroll
            for (int ci = 0; ci < 4; ci++)
                vf[ci] = *(const v4i*)(vb + (long)ci * 16 * 4096 + mb * 32);
            __builtin_amdgcn_s_setprio(1);
#pragma unroll
            for (int ci = 0; ci < 4; ci++)
#pragma unroll
                for (int qi = 0; qi < 4; qi++)
                    oacc[ci][qi] = mfma16(vf[ci], pf[qi], oacc[ci][qi]);
            __builtin_amdgcn_s_setprio(0);
        }
        __syncthreads();   // drains vmcnt (stage complete) + orders P reads
    }

    // reduce denominator across the 16-lane group (covers all m)
#pragma unroll
    for (int r = 0; r < 4; r++) {
        float s = dacc[r];
        s += __shfl_xor(s, 1); s += __shfl_xor(s, 2);
        s += __shfl_xor(s, 4); s += __shfl_xor(s, 8);
        if (l15 == 0) den[w * 16 + lg * 4 + r] = s;
    }
    __syncthreads();

    // epilogue: scale by gamma/den, write both layouts
    for (int qi = 0; qi < 4; qi++) {
        int q = qi * 16 + l15;
        float sc = gamma / den[q];
        int n = qb * 64 + q;
        for (int ci = 0; ci < 4; ci++) {
            int c0 = w * 64 + ci * 16 + lg * 4;
            ushort4 pk;
            pk.x = f2b(oacc[ci][qi][0] * sc);
            pk.y = f2b(oacc[ci][qi][1] * sc);
            pk.z = f2b(oacc[ci][qi][2] * sc);
            pk.w = f2b(oacc[ci][qi][3] * sc);
            *(ushort4*)(Otb + (long)n * 256 + c0) = pk;
            Onb[(long)(c0 + 0) * 4096 + n] = pk.x;
            Onb[(long)(c0 + 1) * 4096 + n] = pk.y;
            Onb[(long)(c0 + 2) * 4096 + n] = pk.z;
            Onb[(long)(c0 + 3) * 4096 + n] = pk.w;
        }
    }
}

// ---------- final gate + combine ----------
__global__ __launch_bounds__(256) void combine_kernel(
    const u16* __restrict__ On, const u16* __restrict__ O2n,
    const u16* __restrict__ H5, const u16* __restrict__ H6,
    const float* __restrict__ x, float* __restrict__ out)
{
    long i = ((long)blockIdx.x * 256 + threadIdx.x) * 4;
    ushort4 a  = *(const ushort4*)(On + i);
    ushort4 c2 = *(const ushort4*)(O2n + i);
    ushort4 h5 = *(const ushort4*)(H5 + i);
    ushort4 h6 = *(const ushort4*)(H6 + i);
    float4 xv = *(const float4*)(x + i);
    u16 av[4] = {a.x, a.y, a.z, a.w};
    u16 cv[4] = {c2.x, c2.y, c2.z, c2.w};
    u16 h5v[4] = {h5.x, h5.y, h5.z, h5.w};
    u16 h6v[4] = {h6.x, h6.y, h6.z, h6.w};
    float xr[4] = {xv.x, xv.y, xv.z, xv.w};
    float o[4];
#pragma unroll
    for (int j = 0; j < 4; j++) {
        float s5 = 1.f / (1.f + __expf(-b2f(h5v[j])));
        float s6 = 1.f / (1.f + __expf(-b2f(h6v[j])));
        float w0 = 1.f / (1.f + __expf(s6 - s5));   // softmax([s5,s6])[0]
        o[j] = w0 * b2f(av[j]) + (1.f - w0) * b2f(cv[j]) + xr[j];
    }
    *(float4*)(out + i) = make_float4(o[0], o[1], o[2], o[3]);
}

// ---------- host ----------
extern "C" void kernel_launch(void* const* d_in, const int* in_sizes, int n_in,
                              void* d_out, int out_size, void* d_ws, size_t ws_size,
                              hipStream_t stream)
{
    const float* x     = (const float*)d_in[0];
    const float* y     = (const float*)d_in[1];
    const float* z     = (const float*)d_in[2];
    const float* m     = (const float*)d_in[3];
    const float* Wv    = (const float*)d_in[4];
    const float* Wv2   = (const float*)d_in[5];
    const float* Wq    = (const float*)d_in[6];
    const float* bq    = (const float*)d_in[7];
    const float* Wk    = (const float*)d_in[8];
    const float* bk    = (const float*)d_in[9];
    const float* Wq2   = (const float*)d_in[10];
    const float* bq2   = (const float*)d_in[11];
    const float* Wk2   = (const float*)d_in[12];
    const float* bk2   = (const float*)d_in[13];
    const float* Win1  = (const float*)d_in[14];
    const float* bin1  = (const float*)d_in[15];
    const float* Win3  = (const float*)d_in[16];
    const float* bin3  = (const float*)d_in[17];
    const float* Wtr   = (const float*)d_in[18];
    const float* btr   = (const float*)d_in[19];
    const float* Wout2 = (const float*)d_in[20];
    const float* bout2 = (const float*)d_in[21];
    const float* Wout3 = (const float*)d_in[22];
    const float* bout3 = (const float*)d_in[23];
    const float* Wfc   = (const float*)d_in[24];
    const float* bfc   = (const float*)d_in[25];
    const float* gamma  = (const float*)d_in[26];
    const float* gamma2 = (const float*)d_in[27];

    char* ws = (char*)d_ws;
    u16* Wb[10];
    for (int i = 0; i < 10; i++) Wb[i] = (u16*)(ws + (size_t)i * 131072);
    u16* Wtrb = (u16*)(ws + 1310720);
    u16* Fb   = (u16*)(ws + 2097152);
    float* zv    = (float*)(ws + 2621440);
    float* mline = (float*)(ws + 2768896);
    auto SLOT = [&](int i) { return ws + 4194304 + (size_t)i * 8388608; };
    u16* xt  = (u16*)SLOT(0);
    u16* yt  = (u16*)SLOT(1);
    u16* yvt = (u16*)SLOT(2);
    u16* fmt = (u16*)SLOT(3);
    u16* fmn = (u16*)SLOT(4);
    u16* v2n = (u16*)SLOT(5);
    u16* qt  = (u16*)SLOT(6);
    u16* kt  = (u16*)SLOT(7);
    u16* q2t = (u16*)SLOT(8);
    u16* k2t = (u16*)SLOT(9);
    u16* O2n = (u16*)SLOT(0);   // xt dead
    u16* Ot_ = (u16*)SLOT(1);   // yt dead
    u16* On_ = (u16*)SLOT(2);   // yvt dead
    u16* O2t = (u16*)SLOT(3);   // fmt dead
    u16* H13 = (u16*)SLOT(4);   // spans S4,S5
    u16* Htra = (u16*)SLOT(6);  // spans S6,S7
    u16* H5  = (u16*)SLOT(8);
    u16* H6  = (u16*)SLOT(9);

    const long NC = 4096L * 256, N512 = 4096L * 512, CC = 65536;

    // 1. convert weights
    WCvt wc;
    const float* wsrc[11] = {Wv, Wv2, Wq, Wk, Wq2, Wk2, Win1, Win3, Wout2, Wout3, Wtr};
    u16* wdst[11] = {Wb[0], Wb[1], Wb[2], Wb[3], Wb[4], Wb[5], Wb[6], Wb[7], Wb[8], Wb[9], Wtrb};
    for (int i = 0; i < 11; i++) { wc.s[i] = wsrc[i]; wc.d[i] = wdst[i]; wc.n[i] = (i == 10) ? 262144 : 65536; }
    cvt_weights<<<dim3(1024, 11), 256, 0, stream>>>(wc);

    // 2. transpose+convert x,y
    transpose_cvt<<<dim3(128, 8, 8), dim3(32, 8), 0, stream>>>(x, y, xt, yt);

    // 3. small path
    small_zm<<<dim3(256, 4), 64, 0, stream>>>(z, m, Wv, Wfc, bfc, zv, mline);
    small_F<<<dim3(256, 4), 256, 0, stream>>>(zv, mline, Fb);

    auto mkdesc = [](const u16* X, int ldx, long xbs, const u16* W, int ldw, long wbs,
                     const float* bias, u16* outT, int ldot, long otbs,
                     u16* outN, int ldon, long onbs, int K) {
        GDesc g; g.X = X; g.W = W; g.bias = bias; g.outT = outT; g.outN = outN;
        g.xbs = xbs; g.wbs = wbs; g.otbs = otbs; g.onbs = onbs;
        g.ldx = ldx; g.ldw = ldw; g.ldot = ldot; g.ldon = ldon; g.K = K;
        return g;
    };

    // 4a. JOB_A: {yvt, qt, q2t, k2t, v2n}  (5 descs x 2 oblks = grid.y 10)
    {
        GJob j{}; j.oblk = 2;
        j.d[0] = mkdesc(yt, 256, NC, Wb[0], 256, 0, nullptr, yvt, 256, NC, nullptr, 0, 0, 256);
        j.d[1] = mkdesc(xt, 256, NC, Wb[2], 256, 0, bq,  qt,  256, NC, nullptr, 0, 0, 256);
        j.d[2] = mkdesc(xt, 256, NC, Wb[4], 256, 0, bq2, q2t, 256, NC, nullptr, 0, 0, 256);
        j.d[3] = mkdesc(xt, 256, NC, Wb[5], 256, 0, bk2, k2t, 256, NC, nullptr, 0, 0, 256);
        j.d[4] = mkdesc(xt, 256, NC, Wb[1], 256, 0, nullptr, nullptr, 0, 0, v2n, 4096, NC, 256);
        gemm_tn<<<dim3(32, 10, 4), 256, 0, stream>>>(j);
    }
    // 4b. JOB_B: fuse_mzy = yv * (F+I)^T  -> fmt [N,C] and fmn [C,N]
    {
        GJob j{}; j.oblk = 2;
        j.d[0] = mkdesc(yvt, 256, NC, Fb, 256, CC, nullptr, fmt, 256, NC, fmn, 4096, NC, 256);
        gemm_tn<<<dim3(32, 2, 4), 256, 0, stream>>>(j);
    }
    // 4c. JOB_C: kt = fmt * Wk^T + bk
    {
        GJob j{}; j.oblk = 2;
        j.d[0] = mkdesc(fmt, 256, NC, Wb[3], 256, 0, bk, kt, 256, NC, nullptr, 0, 0, 256);
        gemm_tn<<<dim3(32, 2, 4), 256, 0, stream>>>(j);
    }

    // 5. both attention branches
    attn_kernel<<<dim3(64, 2, 4), 256, 0, stream>>>(qt, kt, fmn, Ot_, On_, gamma,
                                                    q2t, k2t, v2n, O2t, O2n, gamma2);

    // 6a. JOB_D: {H1, H3} -> H13 [N,512]
    {
        GJob j{}; j.oblk = 2;
        j.d[0] = mkdesc(Ot_, 256, NC, Wb[6], 256, 0, bin1, H13,       512, N512, nullptr, 0, 0, 256);
        j.d[1] = mkdesc(O2t, 256, NC, Wb[7], 256, 0, bin3, H13 + 256, 512, N512, nullptr, 0, 0, 256);
        gemm_tn<<<dim3(32, 4, 4), 256, 0, stream>>>(j);
    }
    // 6b. JOB_E: Htra = H13 * Wtr^T + btr  (K=512, O=512)
    {
        GJob j{}; j.oblk = 4;
        j.d[0] = mkdesc(H13, 512, N512, Wtrb, 512, 0, btr, Htra, 512, N512, nullptr, 0, 0, 512);
        gemm_tn<<<dim3(32, 4, 4), 256, 0, stream>>>(j);
    }
    // 6c. JOB_F: {H5, H6} natural [C,N]
    {
        GJob j{}; j.oblk = 2;
        j.d[0] = mkdesc(Htra,       512, N512, Wb[8], 256, 0, bout2, nullptr, 0, 0, H5, 4096, NC, 256);
        j.d[1] = mkdesc(Htra + 256, 512, N512, Wb[9], 256, 0, bout3, nullptr, 0, 0, H6, 4096, NC, 256);
        gemm_tn<<<dim3(32, 4, 4), 256, 0, stream>>>(j);
    }

    // 7. combine
    combine_kernel<<<4096, 256, 0, stream>>>(On_, O2n, H5, H6, x, (float*)d_out);
}